// Round 7
// baseline (115.097 us; speedup 1.0000x reference)
//
#include <hip/hip_runtime.h>
#include <cstdint>
#include <cstddef>

// Problem constants: B=1024, T=12, D=512
#define Bsz 1024
#define Tsz 12
#define Dsz 512

#define NIB 16           // 64-wide i slots per (t,j) row
#define NKS 16           // K-steps of 32

typedef _Float16 f16x8 __attribute__((ext_vector_type(8)));
typedef float    f32x4 __attribute__((ext_vector_type(4)));

// 8 fp32 -> 8 f16 (RNE). Single-term f16 dots: loss error ~1e-4 vs harness
// threshold 1.47 (validated round 6: absmax reported 0.0).
__device__ __forceinline__ f16x8 cvt8(const f32x4 v0, const f32x4 v1) {
    f16x8 h;
#pragma unroll
    for (int e = 0; e < 4; ++e) {
        h[e]     = (_Float16)v0[e];
        h[e + 4] = (_Float16)v1[e];
    }
    return h;
}

// One-time fp32 -> f16 conversion into MFMA FRAGMENT ORDER:
//   Ff[t][rb][ks][lane][e]  =  src[b = rb*16 + (lane&15)][t][d = ks*32 + (lane>>4)*8 + e]
// so the GEMM loads each fragment as ONE coalesced 1KB global_load_dwordx4
// per wave -- no LDS, no barriers, no per-step conversion in the GEMM.
// One wave handles one (arr, t, rb, ks): reads 16 rows x 128B contiguous,
// writes the wave's contiguous 1KB (lane outputs are a permutation).
__global__ __launch_bounds__(256) void convert_kernel(
    const float* __restrict__ P, const float* __restrict__ X,
    _Float16* __restrict__ Af, _Float16* __restrict__ Bf,
    float* __restrict__ out)
{
    if (blockIdx.x == 0 && blockIdx.y == 0 && blockIdx.z == 0 && threadIdx.x < 2)
        out[threadIdx.x] = 0.0f;   // re-zero per replay (runs before combine)

    const int tid  = threadIdx.x;
    const int w    = tid >> 6;
    const int lane = tid & 63;
    const int rb   = blockIdx.x >> 2;                 // 0..63 (16-row block)
    const int ks   = ((blockIdx.x & 3) << 2) + w;     // 0..15 (32-k step)
    const int t    = blockIdx.y;
    const int arr  = blockIdx.z;                      // 0 = P -> Af, 1 = X -> Bf

    const float* src = arr ? X : P;
    _Float16*    dst = arr ? Bf : Af;

    // read side: 4 consecutive lanes cover one row's 128B (coalesced)
    const int bl   = lane >> 2;      // row in block, 0..15
    const int doct = lane & 3;       // which 8-f32 chunk of the 32-k step
    const float* s = src + ((size_t)(rb * 16 + bl) * Tsz + t) * Dsz
                   + (size_t)ks * 32 + doct * 8;
    const f32x4 v0 = *(const f32x4*)s;
    const f32x4 v1 = *(const f32x4*)(s + 4);

    // write side: fragment lane lo = (lane&15 of MFMA) + 16*quad
    const int lo = bl + (doct << 4);
    _Float16* dp = dst + ((((size_t)t * 64 + rb) * 16 + ks) * 64 + lo) * 8;
    *(f16x8*)dp = cvt8(v0, v1);
}

// Fused GEMM + per-wave softmax partials. dots[t,i,j] = <P[j,t,:], X[i,t,:]>.
// Round-6 diagnosis: 2-phase LDS structure was stall-bound (all pipes <25%,
// wall 4x pipe-sum) -- barriers + LDS round-trip serialize. This version has
// NO LDS, NO barriers, NO staging: fragments load directly from the
// fragment-ordered f16 arrays as coalesced b128 loads; waves are fully
// independent so TLP (12 waves/CU) hides all latency. Block = 4 waves on the
// SAME 64-row j-strip (A fragment addresses are IDENTICAL across the 4 waves
// -> L1 broadcast), wave tile 64x64. Per-step: 8 loads + 16 MFMA.
__global__ __launch_bounds__(256, 3) void gemm_fused_kernel(
    const _Float16* __restrict__ Af,   // P fragments (A side, j rows)
    const _Float16* __restrict__ Bf,   // X fragments (B side, i rows)
    float* __restrict__ pm,            // [Tsz*Bsz*NIB] slot max
    float* __restrict__ ps,            // [Tsz*Bsz*NIB] slot sum exp
    int*   __restrict__ pa,            // [Tsz*Bsz*NIB] slot argmax (global i)
    float* __restrict__ diag)          // [Tsz*Bsz]
{
    // ---- XCD-chunked bijective remap (768 % 8 == 0): per-t f16 working set
    // (2 MB) L2-resident per XCD. Evidence: FETCH 130->30 MB (rounds 2/4/6).
    const int orig = blockIdx.x + (blockIdx.y << 2) + (blockIdx.z << 6);
    const int wgid = (orig & 7) * 96 + (orig >> 3);
    const int t      = wgid >> 6;        // 64 blocks per t-plane
    const int rem    = wgid & 63;
    const int jstrip = rem >> 2;         // 16 j-strips of 64 rows
    const int ic     = rem & 3;          // 4 i-chunks of 256 cols
    const int jb  = jstrip * 64;

    const int tid  = threadIdx.x;
    const int lane = tid & 63;
    const int w    = tid >> 6;           // wave 0..3
    const int ibw  = ic * 256 + w * 64;  // this wave's i base
    const int ml   = lane & 15;
    const int quad = lane >> 4;

    f32x4 acc[4][4];
#pragma unroll
    for (int r = 0; r < 4; ++r)
#pragma unroll
        for (int c = 0; c < 4; ++c) acc[r][c] = (f32x4){0.f, 0.f, 0.f, 0.f};

    // fragment bases: [t][rb][ks][lane][8]; per-lane = lane*16B
    const _Float16* Ap = Af + ((size_t)(t * 64 + (jb  >> 4)) * 16 * 64 + lane) * 8;
    const _Float16* Bp = Bf + ((size_t)(t * 64 + (ibw >> 4)) * 16 * 64 + lane) * 8;

#pragma unroll 4
    for (int ks = 0; ks < NKS; ++ks) {
        f16x8 ah[4], bh[4];
#pragma unroll
        for (int r = 0; r < 4; ++r)
            ah[r] = *(const f16x8*)(Ap + (size_t)(r * 16 + ks) * 512);
#pragma unroll
        for (int c = 0; c < 4; ++c)
            bh[c] = *(const f16x8*)(Bp + (size_t)(c * 16 + ks) * 512);

#pragma unroll
        for (int r = 0; r < 4; ++r)
#pragma unroll
            for (int c = 0; c < 4; ++c)
                acc[r][c] = __builtin_amdgcn_mfma_f32_16x16x32_f16(ah[r], bh[c], acc[r][c], 0, 0, 0);
    }

    // ---- diag extraction (global index test; epilogue-only) ----
#pragma unroll
    for (int r = 0; r < 4; ++r)
#pragma unroll
        for (int v = 0; v < 4; ++v) {
            const int jg = jb + r * 16 + quad * 4 + v;
#pragma unroll
            for (int c = 0; c < 4; ++c) {
                const int ig = ibw + c * 16 + ml;
                if (ig == jg) diag[(size_t)t * Bsz + jg] = acc[r][c][v];
            }
        }

    // ---- per-row (j) partial over this wave's private 64-i slot ----
    // acc[r][c][v]: row j = jb+r*16+quad*4+v, col i = ibw+c*16+ml.
    // Wave exclusively owns slot (t, j, ibw/64): direct global write, no LDS.
#pragma unroll
    for (int r = 0; r < 4; ++r)
#pragma unroll
        for (int v = 0; v < 4; ++v) {
            float m = acc[r][0][v];
            int   ai = ml;
#pragma unroll
            for (int c = 1; c < 4; ++c) {
                const float val = acc[r][c][v];
                if (val > m) { m = val; ai = c * 16 + ml; }  // ascending c -> smaller i on ties
            }
#pragma unroll
            for (int off = 1; off < 16; off <<= 1) {   // stays within quad group
                const float om = __shfl_xor(m, off);
                const int   oi = __shfl_xor(ai, off);
                if (om > m || (om == m && oi < ai)) { m = om; ai = oi; }
            }
            float s = 0.0f;
#pragma unroll
            for (int c = 0; c < 4; ++c) s += __expf(acc[r][c][v] - m);
#pragma unroll
            for (int off = 1; off < 16; off <<= 1) s += __shfl_xor(s, off);

            if (ml == 0) {
                const int row = jb + r * 16 + quad * 4 + v;
                const size_t slot = ((size_t)t * Bsz + row) * NIB + (ibw >> 6);
                pm[slot] = m;
                ps[slot] = s;
                pa[slot] = ibw + ai;   // global i
            }
        }
}

// One thread per (t,j) column: merge NIB slot partials, 48 block atomics.
__global__ __launch_bounds__(256) void combine_kernel(
    const float* __restrict__ pm,
    const float* __restrict__ ps,
    const int*   __restrict__ pa,
    const float* __restrict__ diag,
    float* __restrict__ out)
{
    const int col = blockIdx.x * 256 + threadIdx.x;   // 0..Tsz*Bsz-1
    const int j = col & (Bsz - 1);

    const size_t base = (size_t)col * NIB;
    float M = pm[base]; int A = pa[base];
#pragma unroll
    for (int b = 1; b < NIB; ++b) {
        const float mb = pm[base + b];
        if (mb > M) { M = mb; A = pa[base + b]; }   // tie -> earlier b = smaller i
    }
    float S = 0.0f;
#pragma unroll
    for (int b = 0; b < NIB; ++b) S += ps[base + b] * __expf(pm[base + b] - M);

    const float lse = M + logf(S);
    float sl = lse - diag[col];
    float sc = (A == j) ? 1.0f : 0.0f;

#pragma unroll
    for (int off = 1; off < 64; off <<= 1) {
        sl += __shfl_xor(sl, off);
        sc += __shfl_xor(sc, off);
    }

    __shared__ float wl[4], wc[4];
    const int w = threadIdx.x >> 6;
    if ((threadIdx.x & 63) == 0) { wl[w] = sl; wc[w] = sc; }
    __syncthreads();
    if (threadIdx.x == 0) {
        const float inv = 1.0f / (float)(Bsz * Tsz);
        atomicAdd(&out[0], (wl[0] + wl[1] + wl[2] + wl[3]) * inv);  // -loss
        atomicAdd(&out[1], (wc[0] + wc[1] + wc[2] + wc[3]) * inv);  // accuracy
    }
}

extern "C" void kernel_launch(void* const* d_in, const int* in_sizes, int n_in,
                              void* d_out, int out_size, void* d_ws, size_t ws_size,
                              hipStream_t stream) {
    const float* P = (const float*)d_in[0];  // predictions [B,T,D]
    const float* X = (const float*)d_in[1];  // x_future_encoded [B,T,D]
    float* out = (float*)d_out;

    const size_t ncol  = (size_t)Bsz * Tsz;          // 12288
    const size_t nslot = ncol * NIB;                 // 196608
    const size_t nel   = (size_t)Bsz * Tsz * Dsz;    // 6,291,456 f16 per array

    float* pm   = (float*)d_ws;
    float* ps   = pm + nslot;
    int*   pa   = (int*)(ps + nslot);
    float* diag = (float*)(pa + nslot);
    _Float16* Af = (_Float16*)(diag + ncol);         // 16B-aligned offset
    _Float16* Bf = Af + nel;                         // total ws ~27.6 MB

    convert_kernel<<<dim3(256, Tsz, 2), dim3(256), 0, stream>>>(P, X, Af, Bf, out);

    gemm_fused_kernel<<<dim3(4, 16, Tsz), dim3(256), 0, stream>>>(
        Af, Bf, pm, ps, pa, diag);

    combine_kernel<<<dim3((int)(ncol / 256)), dim3(256), 0, stream>>>(
        pm, ps, pa, diag, out);
}